// Round 3
// baseline (441.795 us; speedup 1.0000x reference)
//
#include <hip/hip_runtime.h>
#include <hip/hip_bf16.h>

// Problem constants (from reference)
#define GRIDN   14
#define NCELLS  196           // 14*14
#define NB      32            // boxes per image
#define NBATCH  512
#define RECLEN  51            // 1 conf + 20 cls + 2 coord + 14 lx + 14 ly
#define SLICE_ELEMS   39984   // 196*4*51  (one (img,a) slice), fp32
#define IMG_ELEMS     159936  // 4*SLICE_ELEMS
#define QTR_ELEMS     9996    // quarter slice (49 cells * 4 * 51)
#define QTR_VEC4      2499    // QTR_ELEMS*4B / 16B
#define SCALE 0.03125f        // GRID / W = 14 / 448 (exact power of two; W fixed by setup)

// ---------------------------------------------------------------------------
// Fused kernel: one block per (img, a, quarter-slice). fp32 data.
//  - stages 39,984 B of out_four into LDS with 16B vector loads
//  - recomputes the per-image box->cell metadata in LDS (32 boxes),
//    replicating jnp .at[cell].min(arange) via LDS atomicMin
//  - one 51-float record per lane (stride 51: gcd(51,32) via 51%32=19 odd ->
//    exact 2-way bank aliasing, free on gfx950)
//  - wave shfl_xor reduce -> one partial per block (deterministic, no atomics)
// ---------------------------------------------------------------------------
__global__ __launch_bounds__(256) void loss_kernel(
    const float* __restrict__ out4,    // [512,4,196,4,51] fp32
    const float* __restrict__ bb,      // [512,32,4] fp32
    const int* __restrict__ labels,    // [512,32] int32
    float* __restrict__ partial)       // [8192]
{
    __shared__ __align__(16) float tile[QTR_ELEMS];
    __shared__ int   s_wc[NCELLS], s_wz[NCELLS];
    __shared__ float s_pdx[128], s_pdy[128], s_cdx[NB], s_cdy[NB];
    __shared__ int   s_pix[128], s_piy[128], s_cix[NB], s_ciy[NB], s_lab[NB];
    __shared__ float red4[4];

    const int bid = blockIdx.x;
    const int qtr = bid & 3;
    const int a   = (bid >> 2) & 3;
    const int img = bid >> 4;
    const int t   = threadIdx.x;

    // ---- global -> LDS staging of this quarter-slice ----
    const float* src = out4 + (size_t)img * IMG_ELEMS + a * SLICE_ELEMS + qtr * QTR_ELEMS;
    const uint4* gs = (const uint4*)src;
    uint4* ls = (uint4*)tile;
    for (int i = t; i < QTR_VEC4; i += 256) ls[i] = gs[i];

    // ---- per-image metadata (contract OFF so floor boundaries match np) ----
    if (t < NCELLS) { s_wc[t] = 128; s_wz[t] = 32; }
    if (t < NB) {
#pragma clang fp contract(off)
        const float* q = bb + ((size_t)img * NB + t) * 4;
        float x0 = q[0] * SCALE;
        float y0 = q[1] * SCALE;
        float w  = q[2] * SCALE;
        float h  = q[3] * SCALE;
        float x1 = x0 + w, y1 = y0 + h;
        float cx = x0 + w * 0.5f, cy = y0 + h * 0.5f;
        float fcx = fminf(fmaxf(floorf(cx), 0.f), (float)(GRIDN - 1));
        float fcy = fminf(fmaxf(floorf(cy), 0.f), (float)(GRIDN - 1));
        s_cix[t] = (int)fcx; s_ciy[t] = (int)fcy;
        s_cdx[t] = cx - fcx; s_cdy[t] = cy - fcy;
        s_lab[t] = labels[(size_t)img * NB + t];
        #pragma unroll
        for (int c = 0; c < 4; ++c) {   // px=[x0,x1,x0,x1], py=[y0,y0,y1,y1]
            float px = (c & 1) ? x1 : x0;
            float py = (c & 2) ? y1 : y0;
            float fpx = fminf(fmaxf(floorf(px), 0.f), (float)(GRIDN - 1));
            float fpy = fminf(fmaxf(floorf(py), 0.f), (float)(GRIDN - 1));
            s_pix[t * 4 + c] = (int)fpx; s_piy[t * 4 + c] = (int)fpy;
            s_pdx[t * 4 + c] = px - fpx; s_pdy[t * 4 + c] = py - fpy;
        }
    }
    __syncthreads();   // tile staged + meta arrays written
    if (t < 128) atomicMin(&s_wc[s_pix[t] * GRIDN + s_piy[t]], t);  // t = 4*box+corner
    if (t < NB)  atomicMin(&s_wz[s_cix[t] * GRIDN + s_ciy[t]], t);  // t = box
    __syncthreads();

    // ---- per-record loss (196 records, one per lane for t<196) ----
    float sum = 0.f;
    for (int r = t; r < 49 * 4; r += 256) {
        const float* v = tile + r * RECLEN;
        const int cellg = qtr * 49 + (r >> 2);   // global cell id 0..195
        const int b = r & 3;

        float conf = v[0];
        float s_cls = 0.f, s_lx = 0.f, s_ly = 0.f;
        #pragma unroll
        for (int k = 1; k <= 20; ++k) { float x = v[k]; s_cls += x * x; }
        float c1 = v[21], c2 = v[22];
        #pragma unroll
        for (int k = 23; k <= 36; ++k) { float x = v[k]; s_lx += x * x; }
        #pragma unroll
        for (int k = 37; k <= 50; ++k) { float x = v[k]; s_ly += x * x; }

        float tx, ty; int lab, jx, jy, msk;
        if (b < 2) {            // corner branch
            int wc = s_wc[cellg]; msk = (wc < 128); int w0 = msk ? wc : 0; int bx = w0 >> 2;
            tx = s_pdx[w0]; ty = s_pdy[w0];
            lab = s_lab[bx]; jx = s_cix[bx]; jy = s_ciy[bx];
        } else {                // center branch (lx/ly targets depend on axis a)
            int wz = s_wz[cellg]; msk = (wz < NB); int z0 = msk ? wz : 0;
            tx = s_cdx[z0]; ty = s_cdy[z0]; lab = s_lab[z0];
            jx = s_pix[z0 * 4 + a]; jy = s_piy[z0 * 4 + a];
        }
        float xl = v[1 + lab];
        float xx = v[23 + jx];
        float xy = v[37 + jy];

        float pt = (conf - 1.f) * (conf - 1.f)
                 + (s_cls - 2.f * xl + 1.f) * (1.f / 20.f)
                 + ((c1 - tx) * (c1 - tx) + (c2 - ty) * (c2 - ty)) * 0.5f
                 + (s_lx - 2.f * xx + 1.f) * (1.f / 14.f)
                 + (s_ly - 2.f * xy + 1.f) * (1.f / 14.f);
        sum += msk ? pt : conf * conf;
    }

    // ---- reduce 256 lanes -> 1 ----
    #pragma unroll
    for (int off = 32; off > 0; off >>= 1) sum += __shfl_xor(sum, off, 64);
    if ((t & 63) == 0) red4[t >> 6] = sum;
    __syncthreads();
    if (t == 0) partial[bid] = red4[0] + red4[1] + red4[2] + red4[3];
}

// ---------------------------------------------------------------------------
// Fold the 4 quarter-slice partials per (img,a), emit fp32.
// ---------------------------------------------------------------------------
__global__ void fin_kernel(const float* __restrict__ partial, float* __restrict__ out)
{
    int i = blockIdx.x * blockDim.x + threadIdx.x;
    if (i < NBATCH * 4)
        out[i] = (partial[4 * i] + partial[4 * i + 1]) + (partial[4 * i + 2] + partial[4 * i + 3]);
}

extern "C" void kernel_launch(void* const* d_in, const int* in_sizes, int n_in,
                              void* d_out, int out_size, void* d_ws, size_t ws_size,
                              hipStream_t stream)
{
    // inputs: 0=out_four (fp32), 1=bboxes (fp32), 2=labels (int32), 3=H, 4=W (unused; fixed 448)
    const float* out4   = (const float*)d_in[0];
    const float* bboxes = (const float*)d_in[1];
    const int*   labels = (const int*)d_in[2];

    float* partial = (float*)d_ws;   // 8192 * 4 B = 32 KiB

    hipLaunchKernelGGL(loss_kernel, dim3(NBATCH * 16), dim3(256), 0, stream,
                       out4, bboxes, labels, partial);
    hipLaunchKernelGGL(fin_kernel, dim3(8), dim3(256), 0, stream,
                       partial, (float*)d_out);
}

// Round 4
// 429.764 us; speedup vs baseline: 1.0280x; 1.0280x over previous
//
#include <hip/hip_runtime.h>
#include <hip/hip_bf16.h>

// Problem constants (from reference)
#define GRIDN   14
#define NCELLS  196           // 14*14
#define NB      32            // boxes per image
#define NBATCH  512
#define RECLEN  51            // 1 conf + 20 cls + 2 coord + 14 lx + 14 ly
#define SLICE_ELEMS   39984   // 196*4*51  (one (img,a) slice), fp32
#define IMG_ELEMS     159936  // 4*SLICE_ELEMS
#define QTR_ELEMS     9996    // quarter slice (49 cells * 4 * 51)
#define QTR_VEC4      2499    // QTR_ELEMS*4B / 16B   (= 9*256 + 195)
#define SCALE 0.03125f        // GRID / W = 14 / 448 (exact power of two; W fixed by setup)

// ---------------------------------------------------------------------------
// Fused kernel: one block per (img, a, quarter-slice). fp32 data.
//  - stages 39,984 B of out_four straight into LDS via global_load_lds
//    width=16 (no VGPR round-trip; layout is wave-uniform base + lane*16,
//    which is exactly what the instruction requires)
//  - recomputes the per-image box->cell metadata in LDS (32 boxes),
//    replicating jnp .at[cell].min(arange) via LDS atomicMin
//  - one 51-float record per lane (stride 51 -> exact 2-way bank aliasing,
//    free on gfx950)
//  - wave shfl_xor reduce -> one partial per block (deterministic, no atomics)
// ---------------------------------------------------------------------------
__global__ __launch_bounds__(256) void loss_kernel(
    const float* __restrict__ out4,    // [512,4,196,4,51] fp32
    const float* __restrict__ bb,      // [512,32,4] fp32
    const int* __restrict__ labels,    // [512,32] int32
    float* __restrict__ partial)       // [8192]
{
    __shared__ __align__(16) float tile[QTR_ELEMS];
    __shared__ int   s_wc[NCELLS], s_wz[NCELLS];
    __shared__ float s_pdx[128], s_pdy[128], s_cdx[NB], s_cdy[NB];
    __shared__ int   s_pix[128], s_piy[128], s_cix[NB], s_ciy[NB], s_lab[NB];
    __shared__ float red4[4];

    const int bid = blockIdx.x;
    const int qtr = bid & 3;
    const int a   = (bid >> 2) & 3;
    const int img = bid >> 4;
    const int t   = threadIdx.x;

    // ---- global -> LDS staging of this quarter-slice (async, width=16) ----
    const float* src = out4 + (size_t)img * IMG_ELEMS + a * SLICE_ELEMS + qtr * QTR_ELEMS;
    {
        const uint4* gs = (const uint4*)src;
        uint4* ls = (uint4*)tile;
        #pragma unroll
        for (int i = 0; i < 10; ++i) {
            int idx = i * 256 + t;
            if (idx < QTR_VEC4) {
                __builtin_amdgcn_global_load_lds(
                    (const __attribute__((address_space(1))) void*)(gs + idx),
                    (__attribute__((address_space(3))) void*)(ls + idx),
                    16, 0, 0);
            }
        }
    }

    // ---- per-image metadata (contract OFF so floor boundaries match np) ----
    if (t < NCELLS) { s_wc[t] = 128; s_wz[t] = 32; }
    if (t < NB) {
#pragma clang fp contract(off)
        const float* q = bb + ((size_t)img * NB + t) * 4;
        float x0 = q[0] * SCALE;
        float y0 = q[1] * SCALE;
        float w  = q[2] * SCALE;
        float h  = q[3] * SCALE;
        float x1 = x0 + w, y1 = y0 + h;
        float cx = x0 + w * 0.5f, cy = y0 + h * 0.5f;
        float fcx = fminf(fmaxf(floorf(cx), 0.f), (float)(GRIDN - 1));
        float fcy = fminf(fmaxf(floorf(cy), 0.f), (float)(GRIDN - 1));
        s_cix[t] = (int)fcx; s_ciy[t] = (int)fcy;
        s_cdx[t] = cx - fcx; s_cdy[t] = cy - fcy;
        s_lab[t] = labels[(size_t)img * NB + t];
        #pragma unroll
        for (int c = 0; c < 4; ++c) {   // px=[x0,x1,x0,x1], py=[y0,y0,y1,y1]
            float px = (c & 1) ? x1 : x0;
            float py = (c & 2) ? y1 : y0;
            float fpx = fminf(fmaxf(floorf(px), 0.f), (float)(GRIDN - 1));
            float fpy = fminf(fmaxf(floorf(py), 0.f), (float)(GRIDN - 1));
            s_pix[t * 4 + c] = (int)fpx; s_piy[t * 4 + c] = (int)fpy;
            s_pdx[t * 4 + c] = px - fpx; s_pdy[t * 4 + c] = py - fpy;
        }
    }
    __syncthreads();   // tile staged (vmcnt drained) + meta arrays written
    if (t < 128) atomicMin(&s_wc[s_pix[t] * GRIDN + s_piy[t]], t);  // t = 4*box+corner
    if (t < NB)  atomicMin(&s_wz[s_cix[t] * GRIDN + s_ciy[t]], t);  // t = box
    __syncthreads();

    // ---- per-record loss (196 records, one per lane for t<196) ----
    float sum = 0.f;
    for (int r = t; r < 49 * 4; r += 256) {
        const float* v = tile + r * RECLEN;
        const int cellg = qtr * 49 + (r >> 2);   // global cell id 0..195
        const int b = r & 3;

        float conf = v[0];
        float s_cls = 0.f, s_lx = 0.f, s_ly = 0.f;
        #pragma unroll
        for (int k = 1; k <= 20; ++k) { float x = v[k]; s_cls += x * x; }
        float c1 = v[21], c2 = v[22];
        #pragma unroll
        for (int k = 23; k <= 36; ++k) { float x = v[k]; s_lx += x * x; }
        #pragma unroll
        for (int k = 37; k <= 50; ++k) { float x = v[k]; s_ly += x * x; }

        float tx, ty; int lab, jx, jy, msk;
        if (b < 2) {            // corner branch
            int wc = s_wc[cellg]; msk = (wc < 128); int w0 = msk ? wc : 0; int bx = w0 >> 2;
            tx = s_pdx[w0]; ty = s_pdy[w0];
            lab = s_lab[bx]; jx = s_cix[bx]; jy = s_ciy[bx];
        } else {                // center branch (lx/ly targets depend on axis a)
            int wz = s_wz[cellg]; msk = (wz < NB); int z0 = msk ? wz : 0;
            tx = s_cdx[z0]; ty = s_cdy[z0]; lab = s_lab[z0];
            jx = s_pix[z0 * 4 + a]; jy = s_piy[z0 * 4 + a];
        }
        float xl = v[1 + lab];
        float xx = v[23 + jx];
        float xy = v[37 + jy];

        float pt = (conf - 1.f) * (conf - 1.f)
                 + (s_cls - 2.f * xl + 1.f) * (1.f / 20.f)
                 + ((c1 - tx) * (c1 - tx) + (c2 - ty) * (c2 - ty)) * 0.5f
                 + (s_lx - 2.f * xx + 1.f) * (1.f / 14.f)
                 + (s_ly - 2.f * xy + 1.f) * (1.f / 14.f);
        sum += msk ? pt : conf * conf;
    }

    // ---- reduce 256 lanes -> 1 ----
    #pragma unroll
    for (int off = 32; off > 0; off >>= 1) sum += __shfl_xor(sum, off, 64);
    if ((t & 63) == 0) red4[t >> 6] = sum;
    __syncthreads();
    if (t == 0) partial[bid] = red4[0] + red4[1] + red4[2] + red4[3];
}

// ---------------------------------------------------------------------------
// Fold the 4 quarter-slice partials per (img,a), emit fp32.
// ---------------------------------------------------------------------------
__global__ void fin_kernel(const float* __restrict__ partial, float* __restrict__ out)
{
    int i = blockIdx.x * blockDim.x + threadIdx.x;
    if (i < NBATCH * 4)
        out[i] = (partial[4 * i] + partial[4 * i + 1]) + (partial[4 * i + 2] + partial[4 * i + 3]);
}

extern "C" void kernel_launch(void* const* d_in, const int* in_sizes, int n_in,
                              void* d_out, int out_size, void* d_ws, size_t ws_size,
                              hipStream_t stream)
{
    // inputs: 0=out_four (fp32), 1=bboxes (fp32), 2=labels (int32), 3=H, 4=W (unused; fixed 448)
    const float* out4   = (const float*)d_in[0];
    const float* bboxes = (const float*)d_in[1];
    const int*   labels = (const int*)d_in[2];

    float* partial = (float*)d_ws;   // 8192 * 4 B = 32 KiB

    hipLaunchKernelGGL(loss_kernel, dim3(NBATCH * 16), dim3(256), 0, stream,
                       out4, bboxes, labels, partial);
    hipLaunchKernelGGL(fin_kernel, dim3(8), dim3(256), 0, stream,
                       partial, (float*)d_out);
}